// Round 12
// baseline (148.316 us; speedup 1.0000x reference)
//
#include <hip/hip_runtime.h>

#define Bn 8
#define Tn 1024
#define Dn 768
#define Hn 12
#define HDn 64
#define D3 (3 * Dn)

typedef float f32x4 __attribute__((ext_vector_type(4)));
typedef short bf16x8 __attribute__((ext_vector_type(8)));
typedef unsigned short u16;

// softmax computed in exp2 domain: scale = (1/sqrt(64)) * log2(e)
#define SM_SCALE 0.18033688011112042f

__device__ __forceinline__ u16 f2b(float f) {
    unsigned u = __builtin_bit_cast(unsigned, f);
    u += 0x7fffu + ((u >> 16) & 1u);
    return (u16)(u >> 16);
}

__device__ __forceinline__ unsigned cvt_pk_bf16(float lo, float hi) {
    unsigned r;
    asm("v_cvt_pk_bf16_f32 %0, %1, %2" : "=v"(r) : "v"(lo), "v"(hi));
    return r;
}

__device__ __forceinline__ void async_lds16(void* lds, const void* g) {
    __builtin_amdgcn_global_load_lds(
        (const __attribute__((address_space(1))) unsigned int*)g,
        (__attribute__((address_space(3))) unsigned int*)lds, 16, 0, 0);
}

// ---------------------------------------------------------------------------
// fp32 -> bf16 elementwise convert (n divisible by 4)
// ---------------------------------------------------------------------------
__global__ __launch_bounds__(256)
void conv_bf16_kernel(const float* __restrict__ in, u16* __restrict__ out, int n)
{
    int i = (blockIdx.x * 256 + threadIdx.x) * 4;
    if (i >= n) return;
    float4 v = *(const float4*)&in[i];
    union { u16 u[4]; uint2 p; } r;
    r.u[0] = f2b(v.x); r.u[1] = f2b(v.y); r.u[2] = f2b(v.z); r.u[3] = f2b(v.w);
    *(uint2*)&out[i] = r.p;
}

// ---------------------------------------------------------------------------
// W[K][N] fp32 -> WT[N][K] bf16  (64x64 tiles)
// ---------------------------------------------------------------------------
__global__ __launch_bounds__(256)
void transpose_bf16_kernel(const float* __restrict__ W, u16* __restrict__ WT,
                           int K, int N)
{
    __shared__ float Ls[64][65];
    const int bk = blockIdx.y * 64, bn = blockIdx.x * 64;
    const int r  = threadIdx.x >> 2;
    const int c0 = (threadIdx.x & 3) * 16;
    #pragma unroll
    for (int i = 0; i < 4; ++i) {
        float4 v = *(const float4*)&W[(size_t)(bk + r) * N + bn + c0 + i * 4];
        Ls[r][c0 + i * 4 + 0] = v.x;
        Ls[r][c0 + i * 4 + 1] = v.y;
        Ls[r][c0 + i * 4 + 2] = v.z;
        Ls[r][c0 + i * 4 + 3] = v.w;
    }
    __syncthreads();
    #pragma unroll
    for (int i = 0; i < 16; ++i) {
        WT[(size_t)(bn + r) * K + bk + c0 + i] = f2b(Ls[c0 + i][r]);
    }
}

// ---------------------------------------------------------------------------
// bf16 MFMA GEMM, 256x128 block, BK=32, 2-phase stage-early double-buffered
// (round-10 verified staging). NEW: 4 waves (2M x 2N), wave tile = 128x64:
// per K-step per wave = 12 ds_read_b128 (8 A + 4 B) feeding 32 MFMA
// (reads/MFMA 0.375 vs 0.5) -- attacks the measured LDS-read-issue bound.
// LDS 48 KB. LDS swizzle: per 128B row-pair, slot s = (((row&1)<<2)|chunk)
// ^ (rp&7) (source pre-swizzled, LDS dest linear; ds_read 2-way = free).
// 1D grid, XCD-chunked bijective swizzle (nwg%8==0).
// MODE 0: fp32 C.  MODE 1 (QKV): cols<1536 -> bf16 qkv; cols>=1536 -> V
// transposed into VT[b,h,d,t] (packed 4-row 8B stores).
// ---------------------------------------------------------------------------
template <int MODE>
__global__ __launch_bounds__(256)
void gemm_mfma_kernel(const u16* __restrict__ A, const u16* __restrict__ BT,
                      const float* __restrict__ bias, void* __restrict__ Cout,
                      u16* __restrict__ VTout, int M, int N, int K)
{
    constexpr int BM = 256, BN = 128, T = 256;

    __shared__ u16 As[2][BM * 32];   // 16 KB per buffer
    __shared__ u16 Bs[2][BN * 32];   //  8 KB per buffer
    const int tid  = threadIdx.x;
    const int w    = tid >> 6;        // 0..3
    const int lane = tid & 63;
    const int li   = lane & 15;
    const int g    = lane >> 4;
    const int wm   = w >> 1;          // 0..1 (M half, 128 rows)
    const int wn   = w & 1;           // 0..1 (N half, 64 cols)

    // XCD-chunked swizzle (gridDim.x % 8 == 0 guaranteed by launch)
    const int fid = blockIdx.x;
    const int wg  = (fid & 7) * ((int)gridDim.x >> 3) + (fid >> 3);
    const int nbx = N / BN;
    const int bm  = (wg / nbx) * BM;
    const int bn  = (wg % nbx) * BN;

    // stage: chunk (rp = L>>3, s = L&7) holds global
    // (row = 2rp + (u>>2), chunk u&3) where u = s ^ (rp&7).
#define GSTAGE(k0s, buf_) do {                                                 \
        _Pragma("unroll")                                                      \
        for (int i_ = 0; i_ < 4; ++i_) {                                       \
            const int L_  = i_ * T + tid;                                      \
            const int rp_ = L_ >> 3;                                           \
            const int u_  = (L_ & 7) ^ (rp_ & 7);                              \
            const int row_ = rp_ * 2 + (u_ >> 2);                              \
            const int gc_  = u_ & 3;                                           \
            async_lds16(&As[buf_][(i_ * T + w * 64) * 8],                      \
                        &A[(size_t)(bm + row_) * K + (k0s) + gc_ * 8]);        \
        }                                                                      \
        _Pragma("unroll")                                                      \
        for (int i_ = 0; i_ < 2; ++i_) {                                       \
            const int L_  = i_ * T + tid;                                      \
            const int rp_ = L_ >> 3;                                           \
            const int u_  = (L_ & 7) ^ (rp_ & 7);                              \
            const int row_ = rp_ * 2 + (u_ >> 2);                              \
            const int gc_  = u_ & 3;                                           \
            async_lds16(&Bs[buf_][(i_ * T + w * 64) * 8],                      \
                        &BT[(size_t)(bn + row_) * K + (k0s) + gc_ * 8]);       \
        }                                                                      \
    } while (0)

    f32x4 acc[8][4];
    #pragma unroll
    for (int i = 0; i < 8; ++i)
        #pragma unroll
        for (int j = 0; j < 4; ++j)
            acc[i][j] = (f32x4){0.f, 0.f, 0.f, 0.f};

    GSTAGE(0, 0);
    __syncthreads();

    const int nk = K / 32;
    for (int kt = 0; kt < nk; ++kt) {
        const int cur = kt & 1;
        if (kt + 1 < nk) GSTAGE((kt + 1) * 32, cur ^ 1);

        bf16x8 af[8], bfr[4];
        #pragma unroll
        for (int fm = 0; fm < 8; ++fm) {
            const int row = wm * 128 + fm * 16 + li;
            const int rp  = row >> 1;
            const int s   = (((row & 1) << 2) | g) ^ (rp & 7);
            af[fm] = *(const bf16x8*)&As[cur][rp * 64 + s * 8];
        }
        #pragma unroll
        for (int fn = 0; fn < 4; ++fn) {
            const int row = wn * 64 + fn * 16 + li;
            const int rp  = row >> 1;
            const int s   = (((row & 1) << 2) | g) ^ (rp & 7);
            bfr[fn] = *(const bf16x8*)&Bs[cur][rp * 64 + s * 8];
        }
        __builtin_amdgcn_s_setprio(1);
        #pragma unroll
        for (int fm = 0; fm < 8; ++fm)
            #pragma unroll
            for (int fn = 0; fn < 4; ++fn)
                acc[fm][fn] = __builtin_amdgcn_mfma_f32_16x16x32_bf16(
                    af[fm], bfr[fn], acc[fm][fn], 0, 0, 0);
        __builtin_amdgcn_s_setprio(0);

        __syncthreads();   // stage(kt+1) landed; all reads of cur done
    }
#undef GSTAGE

    if (MODE == 1 && bn >= 2 * Dn) {
        // V tile -> VT[b,h,d,t], 4 consecutive t rows packed per 8B store
        #pragma unroll
        for (int fm = 0; fm < 8; ++fm) {
            const int t0g = bm + wm * 128 + fm * 16 + g * 4;
            const int bb = t0g >> 10, tt = t0g & 1023;
            #pragma unroll
            for (int fn = 0; fn < 4; ++fn) {
                const int ncol = bn + wn * 64 + fn * 16 + li;
                const float bs = bias[ncol];
                const int cv = ncol - 2 * Dn;
                const int hv = cv >> 6, dv = cv & 63;
                union { u16 u[4]; uint2 p; } r;
                #pragma unroll
                for (int reg = 0; reg < 4; ++reg)
                    r.u[reg] = f2b(acc[fm][fn][reg] + bs);
                *(uint2*)&VTout[(((size_t)bb * Hn + hv) * HDn + dv) * Tn + tt] = r.p;
            }
        }
    } else {
        #pragma unroll
        for (int fm = 0; fm < 8; ++fm) {
            #pragma unroll
            for (int reg = 0; reg < 4; ++reg) {
                const size_t row = (size_t)(bm + wm * 128 + fm * 16 + g * 4 + reg);
                #pragma unroll
                for (int fn = 0; fn < 4; ++fn) {
                    const int col = bn + wn * 64 + fn * 16 + li;
                    const float v = acc[fm][fn][reg] + bias[col];
                    if (MODE == 1) ((u16*)Cout)[row * N + col] = f2b(v);
                    else           ((float*)Cout)[row * N + col] = v;
                }
            }
        }
    }
}

// ---------------------------------------------------------------------------
// LDS-staged MFMA flash attention (causal), swapped QK^T.  (round-7 verified)
// Block = 256 thr (4 waves), 128 q-rows (32/wave). K and V tiles staged ONCE
// per block via global_load_lds (pre-swizzled source, linear LDS dest),
// double-buffered; stage(kt+1) issued before compute(kt); ONE barrier/tile.
// ---------------------------------------------------------------------------
__global__ __launch_bounds__(256, 3)
void attn_mfma_kernel(const u16* __restrict__ qkvb, const u16* __restrict__ VT,
                      u16* __restrict__ attnb)
{
    __shared__ u16 Ks[2][64 * 64];   // [key][d], octet ^= key&7
    __shared__ u16 Vs[2][64 * 64];   // [d][key], octet ^= d&7
    __shared__ u16 Pb[4][32 * 64];   // per-wave P slice

    const int tid  = threadIdx.x;
    const int w    = tid >> 6;
    const int lane = tid & 63;
    const int li   = lane & 15;
    const int g    = lane >> 4;

    const int fid = blockIdx.x;              // 0..767
    const int xcd = fid & 7, j = fid >> 3;   // j 0..95
    const int bh  = xcd + 8 * (j % 12);      // 0..95
    const int qt  = 7 - (j / 12);            // 7..0 (long first)
    const int b   = bh / 12, h = bh % 12;

    const int q0   = qt * 128;
    const int wrow = q0 + w * 32;            // wave's first q-row
    const size_t rowbase = (size_t)b * Tn;
    const u16* vbase = VT + (size_t)bh * HDn * Tn;           // [d][t]
    const u16* kbase = &qkvb[rowbase * D3 + Dn + h * HDn];

#define STAGE(kt_, buf_) do {                                                  \
        const int k0s = (kt_) * 64;                                            \
        _Pragma("unroll")                                                      \
        for (int i_ = 0; i_ < 2; ++i_) {                                       \
            const int L_   = i_ * 256 + tid;                                   \
            const int row_ = L_ >> 3;                                          \
            const int gp_  = (L_ & 7) ^ (row_ & 7);                            \
            async_lds16(&Ks[buf_][(i_ * 256 + w * 64) * 8],                    \
                        &kbase[(size_t)(k0s + row_) * D3 + gp_ * 8]);          \
            async_lds16(&Vs[buf_][(i_ * 256 + w * 64) * 8],                    \
                        &vbase[(size_t)row_ * Tn + k0s + gp_ * 8]);            \
        }                                                                      \
    } while (0)

    // stage tile 0 first (overlaps with Q loads below)
    STAGE(0, 0);

    // Q fragments (B operand), resident all kernel
    bf16x8 qf[2][2];
    #pragma unroll
    for (int rh = 0; rh < 2; ++rh)
        #pragma unroll
        for (int kc = 0; kc < 2; ++kc)
            qf[rh][kc] = *(const bf16x8*)&qkvb[
                (rowbase + wrow + rh * 16 + li) * D3 + h * HDn + kc * 32 + g * 8];

    f32x4 of[2][4];
    float m_run[2], l_run[2];
    #pragma unroll
    for (int rh = 0; rh < 2; ++rh) {
        #pragma unroll
        for (int nf = 0; nf < 4; ++nf) of[rh][nf] = (f32x4){0.f, 0.f, 0.f, 0.f};
        m_run[rh] = -1e30f;
        l_run[rh] = 0.f;
    }

    const int nkt   = (q0 >> 6) + 2;   // block trip count (waves 2,3 bound)
    const int myend = wrow >> 6;       // this wave's last (diagonal) tile

    __syncthreads();                   // tile 0 staged (vmcnt drained)

    for (int kt = 0; kt < nkt; ++kt) {
        const int cur = kt & 1;
        if (kt + 1 < nkt) STAGE(kt + 1, cur ^ 1);

        if (kt <= myend) {
            const int k0 = kt * 64;
            const bool maskit = (kt == myend);

            // S^T = K Q^T : K frags from LDS (swizzled ds_read_b128)
            f32x4 st[2][4];
            #pragma unroll
            for (int rh = 0; rh < 2; ++rh)
                #pragma unroll
                for (int nf = 0; nf < 4; ++nf) st[rh][nf] = (f32x4){0.f, 0.f, 0.f, 0.f};
            __builtin_amdgcn_s_setprio(1);
            #pragma unroll
            for (int kc = 0; kc < 2; ++kc)
                #pragma unroll
                for (int nf = 0; nf < 4; ++nf) {
                    const bf16x8 kf = *(const bf16x8*)&Ks[cur][
                        (nf * 16 + li) * 64 + ((kc * 32 + g * 8) ^ ((li & 7) * 8))];
                    st[0][nf] = __builtin_amdgcn_mfma_f32_16x16x32_bf16(kf, qf[0][kc], st[0][nf], 0, 0, 0);
                    st[1][nf] = __builtin_amdgcn_mfma_f32_16x16x32_bf16(kf, qf[1][kc], st[1][nf], 0, 0, 0);
                }
            __builtin_amdgcn_s_setprio(0);

            // softmax per row-half (round-6 verified core)
            #pragma unroll
            for (int rh = 0; rh < 2; ++rh) {
                if (maskit) {
                    const int qg = wrow + rh * 16 + li;
                    #pragma unroll
                    for (int nf = 0; nf < 4; ++nf)
                        #pragma unroll
                        for (int reg = 0; reg < 4; ++reg)
                            if (k0 + nf * 16 + g * 4 + reg > qg) st[rh][nf][reg] = -1e30f;
                }

                float mt = st[rh][0][0];
                #pragma unroll
                for (int nf = 0; nf < 4; ++nf)
                    #pragma unroll
                    for (int reg = 0; reg < 4; ++reg)
                        mt = fmaxf(mt, st[rh][nf][reg]);
                mt = fmaxf(mt, __shfl_xor(mt, 16, 64));
                mt = fmaxf(mt, __shfl_xor(mt, 32, 64));
                const float mts = mt * SM_SCALE;

                const float mold = m_run[rh];
                if (!__all(mts <= mold + 8.0f)) {
                    const float mnew = fmaxf(mold, mts);
                    const float resc = exp2f(mold - mnew);
                    m_run[rh] = mnew;
                    l_run[rh] *= resc;
                    float rs[4];
                    #pragma unroll
                    for (int reg = 0; reg < 4; ++reg)
                        rs[reg] = __shfl(resc, g * 4 + reg, 64);
                    #pragma unroll
                    for (int nf = 0; nf < 4; ++nf)
                        #pragma unroll
                        for (int reg = 0; reg < 4; ++reg)
                            of[rh][nf][reg] *= rs[reg];
                }

                const float mcur = m_run[rh];
                float ls = 0.f;
                u16* pb = &Pb[w][(rh * 16 + li) * 64];
                #pragma unroll
                for (int nf = 0; nf < 4; ++nf) {
                    const float p0 = exp2f(fmaf(st[rh][nf][0], SM_SCALE, -mcur));
                    const float p1 = exp2f(fmaf(st[rh][nf][1], SM_SCALE, -mcur));
                    const float p2 = exp2f(fmaf(st[rh][nf][2], SM_SCALE, -mcur));
                    const float p3 = exp2f(fmaf(st[rh][nf][3], SM_SCALE, -mcur));
                    ls += (p0 + p1) + (p2 + p3);
                    uint2 pk;
                    pk.x = cvt_pk_bf16(p0, p1);
                    pk.y = cvt_pk_bf16(p2, p3);
                    *(uint2*)&pb[(nf * 16 + g * 4) ^ ((li & 7) << 3)] = pk;
                }
                ls += __shfl_xor(ls, 16, 64);
                ls += __shfl_xor(ls, 32, 64);
                l_run[rh] += ls;
            }

            // O += P V : P from wave LDS slice, V from staged LDS
            #pragma unroll
            for (int kc = 0; kc < 2; ++kc) {
                const int pcol = (kc * 32 + g * 8) ^ ((li & 7) << 3);
                const bf16x8 pf0 = *(const bf16x8*)&Pb[w][li * 64 + pcol];
                const bf16x8 pf1 = *(const bf16x8*)&Pb[w][(16 + li) * 64 + pcol];
                __builtin_amdgcn_s_setprio(1);
                #pragma unroll
                for (int nf = 0; nf < 4; ++nf) {
                    const bf16x8 vf = *(const bf16x8*)&Vs[cur][
                        (nf * 16 + li) * 64 + ((kc * 32 + g * 8) ^ ((li & 7) * 8))];
                    of[0][nf] = __builtin_amdgcn_mfma_f32_16x16x32_bf16(pf0, vf, of[0][nf], 0, 0, 0);
                    of[1][nf] = __builtin_amdgcn_mfma_f32_16x16x32_bf16(pf1, vf, of[1][nf], 0, 0, 0);
                }
                __builtin_amdgcn_s_setprio(0);
            }
        }

        __syncthreads();   // stage(kt+1) landed; all reads of cur done
    }
#undef STAGE

    // epilogue: normalize (1/l broadcast to O-rows), store bf16 [B*T, D]
    #pragma unroll
    for (int rh = 0; rh < 2; ++rh) {
        const float inv = 1.0f / l_run[rh];
        float rs[4];
        #pragma unroll
        for (int reg = 0; reg < 4; ++reg)
            rs[reg] = __shfl(inv, g * 4 + reg, 64);
        #pragma unroll
        for (int reg = 0; reg < 4; ++reg) {
            const size_t row = rowbase + wrow + rh * 16 + g * 4 + reg;
            #pragma unroll
            for (int nf = 0; nf < 4; ++nf)
                attnb[row * Dn + h * HDn + nf * 16 + li] = f2b(of[rh][nf][reg] * rs[reg]);
        }
    }
}

extern "C" void kernel_launch(void* const* d_in, const int* in_sizes, int n_in,
                              void* d_out, int out_size, void* d_ws, size_t ws_size,
                              hipStream_t stream) {
    const float* x     = (const float*)d_in[0];
    const float* Wqkv  = (const float*)d_in[1];
    const float* bqkv  = (const float*)d_in[2];
    const float* Wproj = (const float*)d_in[3];
    const float* bproj = (const float*)d_in[4];
    float* out = (float*)d_out;

    const int M = Bn * Tn;   // 8192

    char* ws = (char*)d_ws;
    u16* qkvb   = (u16*)ws;  ws += (size_t)M * D3 * 2;        // 37.75 MB
    u16* xb     = (u16*)ws;  ws += (size_t)M * Dn * 2;        // 12.6 MB
    u16* attnb  = (u16*)ws;  ws += (size_t)M * Dn * 2;        // 12.6 MB
    u16* VT     = (u16*)ws;  ws += (size_t)Bn * Hn * HDn * Tn * 2; // 12.6 MB
    u16* WqkvT  = (u16*)ws;  ws += (size_t)D3 * Dn * 2;       // 3.5 MB
    u16* WprojT = (u16*)ws;                                   // 1.2 MB

    conv_bf16_kernel<<<(M * Dn / 4 + 255) / 256, 256, 0, stream>>>(x, xb, M * Dn);
    {
        dim3 gq(D3 / 64, Dn / 64);
        transpose_bf16_kernel<<<gq, 256, 0, stream>>>(Wqkv, WqkvT, Dn, D3);
        dim3 gp(Dn / 64, Dn / 64);
        transpose_bf16_kernel<<<gp, 256, 0, stream>>>(Wproj, WprojT, Dn, Dn);
    }
    {
        const int nwg = (M / 256) * (D3 / 128);   // 576, %8==0
        gemm_mfma_kernel<1><<<nwg, 256, 0, stream>>>(xb, WqkvT, bqkv, qkvb, VT, M, D3, Dn);
    }
    attn_mfma_kernel<<<768, 256, 0, stream>>>(qkvb, VT, attnb);
    {
        const int nwg = (M / 256) * (Dn / 128);   // 192, %8==0
        gemm_mfma_kernel<0><<<nwg, 256, 0, stream>>>(attnb, WprojT, bproj, out, nullptr, M, Dn, Dn);
    }
}

// Round 13
// 117.005 us; speedup vs baseline: 1.2676x; 1.2676x over previous
//
#include <hip/hip_runtime.h>

#define Bn 8
#define Tn 1024
#define Dn 768
#define Hn 12
#define HDn 64
#define D3 (3 * Dn)

typedef float f32x4 __attribute__((ext_vector_type(4)));
typedef short bf16x8 __attribute__((ext_vector_type(8)));
typedef unsigned short u16;

// softmax computed in exp2 domain: scale = (1/sqrt(64)) * log2(e)
#define SM_SCALE 0.18033688011112042f

__device__ __forceinline__ u16 f2b(float f) {
    unsigned u = __builtin_bit_cast(unsigned, f);
    u += 0x7fffu + ((u >> 16) & 1u);
    return (u16)(u >> 16);
}

__device__ __forceinline__ unsigned cvt_pk_bf16(float lo, float hi) {
    unsigned r;
    asm("v_cvt_pk_bf16_f32 %0, %1, %2" : "=v"(r) : "v"(lo), "v"(hi));
    return r;
}

__device__ __forceinline__ void async_lds16(void* lds, const void* g) {
    __builtin_amdgcn_global_load_lds(
        (const __attribute__((address_space(1))) unsigned int*)g,
        (__attribute__((address_space(3))) unsigned int*)lds, 16, 0, 0);
}

// ---------------------------------------------------------------------------
// fp32 -> bf16 elementwise convert (n divisible by 4)
// ---------------------------------------------------------------------------
__global__ __launch_bounds__(256)
void conv_bf16_kernel(const float* __restrict__ in, u16* __restrict__ out, int n)
{
    int i = (blockIdx.x * 256 + threadIdx.x) * 4;
    if (i >= n) return;
    float4 v = *(const float4*)&in[i];
    union { u16 u[4]; uint2 p; } r;
    r.u[0] = f2b(v.x); r.u[1] = f2b(v.y); r.u[2] = f2b(v.z); r.u[3] = f2b(v.w);
    *(uint2*)&out[i] = r.p;
}

// ---------------------------------------------------------------------------
// W[K][N] fp32 -> WT[N][K] bf16  (64x64 tiles)
// ---------------------------------------------------------------------------
__global__ __launch_bounds__(256)
void transpose_bf16_kernel(const float* __restrict__ W, u16* __restrict__ WT,
                           int K, int N)
{
    __shared__ float Ls[64][65];
    const int bk = blockIdx.y * 64, bn = blockIdx.x * 64;
    const int r  = threadIdx.x >> 2;
    const int c0 = (threadIdx.x & 3) * 16;
    #pragma unroll
    for (int i = 0; i < 4; ++i) {
        float4 v = *(const float4*)&W[(size_t)(bk + r) * N + bn + c0 + i * 4];
        Ls[r][c0 + i * 4 + 0] = v.x;
        Ls[r][c0 + i * 4 + 1] = v.y;
        Ls[r][c0 + i * 4 + 2] = v.z;
        Ls[r][c0 + i * 4 + 3] = v.w;
    }
    __syncthreads();
    #pragma unroll
    for (int i = 0; i < 16; ++i) {
        WT[(size_t)(bn + r) * K + bk + c0 + i] = f2b(Ls[c0 + i][r]);
    }
}

// ---------------------------------------------------------------------------
// bf16 MFMA GEMM, tile-templated (BM x BN), BK=32, 2-phase stage-early
// double-buffered (round-8/10 verified loop). Waves = (BM/64)x(BN/64), each
// wave owns a 64x64 sub-tile: 4x4 frags, 16 MFMA/K-step.
// <256,128> reproduces the round-10 verified kernel exactly (QKV);
// <128,128> reproduces the round-8 verified kernel exactly (proj; grid 384
// = 1.5 blocks/CU vs 0.75 at 256-wide -- the measured ~4 us proj win).
// LDS swizzle: per 128B row-pair, slot s = (((row&1)<<2)|chunk) ^ (rp&7)
// (source pre-swizzled, LDS dest linear; ds_read 2-way = free).
// 1D grid, XCD-chunked bijective swizzle (nwg%8==0).
// MODE 0: fp32 C.  MODE 1 (QKV): cols<1536 -> bf16 qkv; cols>=1536 -> V
// transposed into VT[b,h,d,t] (packed 4-row 8B stores).
// ---------------------------------------------------------------------------
template <int MODE, int BM, int BN>
__global__ __launch_bounds__((BM / 64) * (BN / 64) * 64)
void gemm_mfma_kernel(const u16* __restrict__ A, const u16* __restrict__ BT,
                      const float* __restrict__ bias, void* __restrict__ Cout,
                      u16* __restrict__ VTout, int M, int N, int K)
{
    constexpr int WN = BN / 64;
    constexpr int T  = (BM / 64) * WN * 64;   // threads
    constexpr int ACH = BM * 4;               // 16B chunks per A K-slab
    constexpr int BCH = BN * 4;

    __shared__ u16 As[2][BM * 32];
    __shared__ u16 Bs[2][BN * 32];
    const int tid  = threadIdx.x;
    const int w    = tid >> 6;
    const int lane = tid & 63;
    const int li   = lane & 15;
    const int g    = lane >> 4;
    const int wm   = w / WN;
    const int wn   = w % WN;

    // XCD-chunked swizzle (gridDim.x % 8 == 0 guaranteed by launch)
    const int fid = blockIdx.x;
    const int wg  = (fid & 7) * ((int)gridDim.x >> 3) + (fid >> 3);
    const int nbx = N / BN;
    const int bm  = (wg / nbx) * BM;
    const int bn  = (wg % nbx) * BN;

    // stage: chunk (rp = L>>3, s = L&7) holds global
    // (row = 2rp + (u>>2), chunk u&3) where u = s ^ (rp&7).
#define GSTAGE(k0s, buf_) do {                                                 \
        _Pragma("unroll")                                                      \
        for (int i_ = 0; i_ < ACH / T; ++i_) {                                 \
            const int L_  = i_ * T + tid;                                      \
            const int rp_ = L_ >> 3;                                           \
            const int u_  = (L_ & 7) ^ (rp_ & 7);                              \
            const int row_ = rp_ * 2 + (u_ >> 2);                              \
            const int gc_  = u_ & 3;                                           \
            async_lds16(&As[buf_][(i_ * T + w * 64) * 8],                      \
                        &A[(size_t)(bm + row_) * K + (k0s) + gc_ * 8]);        \
        }                                                                      \
        _Pragma("unroll")                                                      \
        for (int i_ = 0; i_ < BCH / T; ++i_) {                                 \
            const int L_  = i_ * T + tid;                                      \
            const int rp_ = L_ >> 3;                                           \
            const int u_  = (L_ & 7) ^ (rp_ & 7);                              \
            const int row_ = rp_ * 2 + (u_ >> 2);                              \
            const int gc_  = u_ & 3;                                           \
            async_lds16(&Bs[buf_][(i_ * T + w * 64) * 8],                      \
                        &BT[(size_t)(bn + row_) * K + (k0s) + gc_ * 8]);       \
        }                                                                      \
    } while (0)

    f32x4 acc[4][4];
    #pragma unroll
    for (int i = 0; i < 4; ++i)
        #pragma unroll
        for (int j = 0; j < 4; ++j)
            acc[i][j] = (f32x4){0.f, 0.f, 0.f, 0.f};

    GSTAGE(0, 0);
    __syncthreads();

    const int nk = K / 32;
    for (int kt = 0; kt < nk; ++kt) {
        const int cur = kt & 1;
        if (kt + 1 < nk) GSTAGE((kt + 1) * 32, cur ^ 1);

        bf16x8 af[4], bfr[4];
        #pragma unroll
        for (int fm = 0; fm < 4; ++fm) {
            const int row = wm * 64 + fm * 16 + li;
            const int rp  = row >> 1;
            const int s   = (((row & 1) << 2) | g) ^ (rp & 7);
            af[fm] = *(const bf16x8*)&As[cur][rp * 64 + s * 8];
        }
        #pragma unroll
        for (int fn = 0; fn < 4; ++fn) {
            const int row = wn * 64 + fn * 16 + li;
            const int rp  = row >> 1;
            const int s   = (((row & 1) << 2) | g) ^ (rp & 7);
            bfr[fn] = *(const bf16x8*)&Bs[cur][rp * 64 + s * 8];
        }
        __builtin_amdgcn_s_setprio(1);
        #pragma unroll
        for (int fm = 0; fm < 4; ++fm)
            #pragma unroll
            for (int fn = 0; fn < 4; ++fn)
                acc[fm][fn] = __builtin_amdgcn_mfma_f32_16x16x32_bf16(
                    af[fm], bfr[fn], acc[fm][fn], 0, 0, 0);
        __builtin_amdgcn_s_setprio(0);

        __syncthreads();   // stage(kt+1) landed; all reads of cur done
    }
#undef GSTAGE

    if (MODE == 1 && bn >= 2 * Dn) {
        // V tile -> VT[b,h,d,t], 4 consecutive t rows packed per 8B store
        #pragma unroll
        for (int fm = 0; fm < 4; ++fm) {
            const int t0g = bm + wm * 64 + fm * 16 + g * 4;
            const int bb = t0g >> 10, tt = t0g & 1023;
            #pragma unroll
            for (int fn = 0; fn < 4; ++fn) {
                const int ncol = bn + wn * 64 + fn * 16 + li;
                const float bs = bias[ncol];
                const int cv = ncol - 2 * Dn;
                const int hv = cv >> 6, dv = cv & 63;
                union { u16 u[4]; uint2 p; } r;
                #pragma unroll
                for (int reg = 0; reg < 4; ++reg)
                    r.u[reg] = f2b(acc[fm][fn][reg] + bs);
                *(uint2*)&VTout[(((size_t)bb * Hn + hv) * HDn + dv) * Tn + tt] = r.p;
            }
        }
    } else {
        #pragma unroll
        for (int fm = 0; fm < 4; ++fm) {
            #pragma unroll
            for (int reg = 0; reg < 4; ++reg) {
                const size_t row = (size_t)(bm + wm * 64 + fm * 16 + g * 4 + reg);
                #pragma unroll
                for (int fn = 0; fn < 4; ++fn) {
                    const int col = bn + wn * 64 + fn * 16 + li;
                    const float v = acc[fm][fn][reg] + bias[col];
                    if (MODE == 1) ((u16*)Cout)[row * N + col] = f2b(v);
                    else           ((float*)Cout)[row * N + col] = v;
                }
            }
        }
    }
}

// ---------------------------------------------------------------------------
// LDS-staged MFMA flash attention (causal), swapped QK^T.  (round-7 verified)
// Block = 256 thr (4 waves), 128 q-rows (32/wave). K and V tiles staged ONCE
// per block via global_load_lds (pre-swizzled source, linear LDS dest),
// double-buffered; stage(kt+1) issued before compute(kt); ONE barrier/tile.
// ---------------------------------------------------------------------------
__global__ __launch_bounds__(256, 3)
void attn_mfma_kernel(const u16* __restrict__ qkvb, const u16* __restrict__ VT,
                      u16* __restrict__ attnb)
{
    __shared__ u16 Ks[2][64 * 64];   // [key][d], octet ^= key&7
    __shared__ u16 Vs[2][64 * 64];   // [d][key], octet ^= d&7
    __shared__ u16 Pb[4][32 * 64];   // per-wave P slice

    const int tid  = threadIdx.x;
    const int w    = tid >> 6;
    const int lane = tid & 63;
    const int li   = lane & 15;
    const int g    = lane >> 4;

    const int fid = blockIdx.x;              // 0..767
    const int xcd = fid & 7, j = fid >> 3;   // j 0..95
    const int bh  = xcd + 8 * (j % 12);      // 0..95
    const int qt  = 7 - (j / 12);            // 7..0 (long first)
    const int b   = bh / 12, h = bh % 12;

    const int q0   = qt * 128;
    const int wrow = q0 + w * 32;            // wave's first q-row
    const size_t rowbase = (size_t)b * Tn;
    const u16* vbase = VT + (size_t)bh * HDn * Tn;           // [d][t]
    const u16* kbase = &qkvb[rowbase * D3 + Dn + h * HDn];

#define STAGE(kt_, buf_) do {                                                  \
        const int k0s = (kt_) * 64;                                            \
        _Pragma("unroll")                                                      \
        for (int i_ = 0; i_ < 2; ++i_) {                                       \
            const int L_   = i_ * 256 + tid;                                   \
            const int row_ = L_ >> 3;                                          \
            const int gp_  = (L_ & 7) ^ (row_ & 7);                            \
            async_lds16(&Ks[buf_][(i_ * 256 + w * 64) * 8],                    \
                        &kbase[(size_t)(k0s + row_) * D3 + gp_ * 8]);          \
            async_lds16(&Vs[buf_][(i_ * 256 + w * 64) * 8],                    \
                        &vbase[(size_t)row_ * Tn + k0s + gp_ * 8]);            \
        }                                                                      \
    } while (0)

    // stage tile 0 first (overlaps with Q loads below)
    STAGE(0, 0);

    // Q fragments (B operand), resident all kernel
    bf16x8 qf[2][2];
    #pragma unroll
    for (int rh = 0; rh < 2; ++rh)
        #pragma unroll
        for (int kc = 0; kc < 2; ++kc)
            qf[rh][kc] = *(const bf16x8*)&qkvb[
                (rowbase + wrow + rh * 16 + li) * D3 + h * HDn + kc * 32 + g * 8];

    f32x4 of[2][4];
    float m_run[2], l_run[2];
    #pragma unroll
    for (int rh = 0; rh < 2; ++rh) {
        #pragma unroll
        for (int nf = 0; nf < 4; ++nf) of[rh][nf] = (f32x4){0.f, 0.f, 0.f, 0.f};
        m_run[rh] = -1e30f;
        l_run[rh] = 0.f;
    }

    const int nkt   = (q0 >> 6) + 2;   // block trip count (waves 2,3 bound)
    const int myend = wrow >> 6;       // this wave's last (diagonal) tile

    __syncthreads();                   // tile 0 staged (vmcnt drained)

    for (int kt = 0; kt < nkt; ++kt) {
        const int cur = kt & 1;
        if (kt + 1 < nkt) STAGE(kt + 1, cur ^ 1);

        if (kt <= myend) {
            const int k0 = kt * 64;
            const bool maskit = (kt == myend);

            // S^T = K Q^T : K frags from LDS (swizzled ds_read_b128)
            f32x4 st[2][4];
            #pragma unroll
            for (int rh = 0; rh < 2; ++rh)
                #pragma unroll
                for (int nf = 0; nf < 4; ++nf) st[rh][nf] = (f32x4){0.f, 0.f, 0.f, 0.f};
            __builtin_amdgcn_s_setprio(1);
            #pragma unroll
            for (int kc = 0; kc < 2; ++kc)
                #pragma unroll
                for (int nf = 0; nf < 4; ++nf) {
                    const bf16x8 kf = *(const bf16x8*)&Ks[cur][
                        (nf * 16 + li) * 64 + ((kc * 32 + g * 8) ^ ((li & 7) * 8))];
                    st[0][nf] = __builtin_amdgcn_mfma_f32_16x16x32_bf16(kf, qf[0][kc], st[0][nf], 0, 0, 0);
                    st[1][nf] = __builtin_amdgcn_mfma_f32_16x16x32_bf16(kf, qf[1][kc], st[1][nf], 0, 0, 0);
                }
            __builtin_amdgcn_s_setprio(0);

            // softmax per row-half (round-6 verified core)
            #pragma unroll
            for (int rh = 0; rh < 2; ++rh) {
                if (maskit) {
                    const int qg = wrow + rh * 16 + li;
                    #pragma unroll
                    for (int nf = 0; nf < 4; ++nf)
                        #pragma unroll
                        for (int reg = 0; reg < 4; ++reg)
                            if (k0 + nf * 16 + g * 4 + reg > qg) st[rh][nf][reg] = -1e30f;
                }

                float mt = st[rh][0][0];
                #pragma unroll
                for (int nf = 0; nf < 4; ++nf)
                    #pragma unroll
                    for (int reg = 0; reg < 4; ++reg)
                        mt = fmaxf(mt, st[rh][nf][reg]);
                mt = fmaxf(mt, __shfl_xor(mt, 16, 64));
                mt = fmaxf(mt, __shfl_xor(mt, 32, 64));
                const float mts = mt * SM_SCALE;

                const float mold = m_run[rh];
                if (!__all(mts <= mold + 8.0f)) {
                    const float mnew = fmaxf(mold, mts);
                    const float resc = exp2f(mold - mnew);
                    m_run[rh] = mnew;
                    l_run[rh] *= resc;
                    float rs[4];
                    #pragma unroll
                    for (int reg = 0; reg < 4; ++reg)
                        rs[reg] = __shfl(resc, g * 4 + reg, 64);
                    #pragma unroll
                    for (int nf = 0; nf < 4; ++nf)
                        #pragma unroll
                        for (int reg = 0; reg < 4; ++reg)
                            of[rh][nf][reg] *= rs[reg];
                }

                const float mcur = m_run[rh];
                float ls = 0.f;
                u16* pb = &Pb[w][(rh * 16 + li) * 64];
                #pragma unroll
                for (int nf = 0; nf < 4; ++nf) {
                    const float p0 = exp2f(fmaf(st[rh][nf][0], SM_SCALE, -mcur));
                    const float p1 = exp2f(fmaf(st[rh][nf][1], SM_SCALE, -mcur));
                    const float p2 = exp2f(fmaf(st[rh][nf][2], SM_SCALE, -mcur));
                    const float p3 = exp2f(fmaf(st[rh][nf][3], SM_SCALE, -mcur));
                    ls += (p0 + p1) + (p2 + p3);
                    uint2 pk;
                    pk.x = cvt_pk_bf16(p0, p1);
                    pk.y = cvt_pk_bf16(p2, p3);
                    *(uint2*)&pb[(nf * 16 + g * 4) ^ ((li & 7) << 3)] = pk;
                }
                ls += __shfl_xor(ls, 16, 64);
                ls += __shfl_xor(ls, 32, 64);
                l_run[rh] += ls;
            }

            // O += P V : P from wave LDS slice, V from staged LDS
            #pragma unroll
            for (int kc = 0; kc < 2; ++kc) {
                const int pcol = (kc * 32 + g * 8) ^ ((li & 7) << 3);
                const bf16x8 pf0 = *(const bf16x8*)&Pb[w][li * 64 + pcol];
                const bf16x8 pf1 = *(const bf16x8*)&Pb[w][(16 + li) * 64 + pcol];
                __builtin_amdgcn_s_setprio(1);
                #pragma unroll
                for (int nf = 0; nf < 4; ++nf) {
                    const bf16x8 vf = *(const bf16x8*)&Vs[cur][
                        (nf * 16 + li) * 64 + ((kc * 32 + g * 8) ^ ((li & 7) * 8))];
                    of[0][nf] = __builtin_amdgcn_mfma_f32_16x16x32_bf16(pf0, vf, of[0][nf], 0, 0, 0);
                    of[1][nf] = __builtin_amdgcn_mfma_f32_16x16x32_bf16(pf1, vf, of[1][nf], 0, 0, 0);
                }
                __builtin_amdgcn_s_setprio(0);
            }
        }

        __syncthreads();   // stage(kt+1) landed; all reads of cur done
    }
#undef STAGE

    // epilogue: normalize (1/l broadcast to O-rows), store bf16 [B*T, D]
    #pragma unroll
    for (int rh = 0; rh < 2; ++rh) {
        const float inv = 1.0f / l_run[rh];
        float rs[4];
        #pragma unroll
        for (int reg = 0; reg < 4; ++reg)
            rs[reg] = __shfl(inv, g * 4 + reg, 64);
        #pragma unroll
        for (int reg = 0; reg < 4; ++reg) {
            const size_t row = rowbase + wrow + rh * 16 + g * 4 + reg;
            #pragma unroll
            for (int nf = 0; nf < 4; ++nf)
                attnb[row * Dn + h * HDn + nf * 16 + li] = f2b(of[rh][nf][reg] * rs[reg]);
        }
    }
}

extern "C" void kernel_launch(void* const* d_in, const int* in_sizes, int n_in,
                              void* d_out, int out_size, void* d_ws, size_t ws_size,
                              hipStream_t stream) {
    const float* x     = (const float*)d_in[0];
    const float* Wqkv  = (const float*)d_in[1];
    const float* bqkv  = (const float*)d_in[2];
    const float* Wproj = (const float*)d_in[3];
    const float* bproj = (const float*)d_in[4];
    float* out = (float*)d_out;

    const int M = Bn * Tn;   // 8192

    char* ws = (char*)d_ws;
    u16* qkvb   = (u16*)ws;  ws += (size_t)M * D3 * 2;        // 37.75 MB
    u16* xb     = (u16*)ws;  ws += (size_t)M * Dn * 2;        // 12.6 MB
    u16* attnb  = (u16*)ws;  ws += (size_t)M * Dn * 2;        // 12.6 MB
    u16* VT     = (u16*)ws;  ws += (size_t)Bn * Hn * HDn * Tn * 2; // 12.6 MB
    u16* WqkvT  = (u16*)ws;  ws += (size_t)D3 * Dn * 2;       // 3.5 MB
    u16* WprojT = (u16*)ws;                                   // 1.2 MB

    conv_bf16_kernel<<<(M * Dn / 4 + 255) / 256, 256, 0, stream>>>(x, xb, M * Dn);
    {
        dim3 gq(D3 / 64, Dn / 64);
        transpose_bf16_kernel<<<gq, 256, 0, stream>>>(Wqkv, WqkvT, Dn, D3);
        dim3 gp(Dn / 64, Dn / 64);
        transpose_bf16_kernel<<<gp, 256, 0, stream>>>(Wproj, WprojT, Dn, Dn);
    }
    {
        const int nwg = (M / 256) * (D3 / 128);   // 576, %8==0
        gemm_mfma_kernel<1, 256, 128><<<nwg, 512, 0, stream>>>(
            xb, WqkvT, bqkv, qkvb, VT, M, D3, Dn);
    }
    attn_mfma_kernel<<<768, 256, 0, stream>>>(qkvb, VT, attnb);
    {
        const int nwg = (M / 128) * (Dn / 128);   // 384, %8==0
        gemm_mfma_kernel<0, 128, 128><<<nwg, 256, 0, stream>>>(
            attnb, WprojT, bproj, out, nullptr, M, Dn, Dn);
    }
}

// Round 14
// 114.434 us; speedup vs baseline: 1.2961x; 1.0225x over previous
//
#include <hip/hip_runtime.h>

#define Bn 8
#define Tn 1024
#define Dn 768
#define Hn 12
#define HDn 64
#define D3 (3 * Dn)

typedef float f32x4 __attribute__((ext_vector_type(4)));
typedef short bf16x8 __attribute__((ext_vector_type(8)));
typedef unsigned short u16;

// softmax computed in exp2 domain: scale = (1/sqrt(64)) * log2(e)
#define SM_SCALE 0.18033688011112042f

__device__ __forceinline__ u16 f2b(float f) {
    unsigned u = __builtin_bit_cast(unsigned, f);
    u += 0x7fffu + ((u >> 16) & 1u);
    return (u16)(u >> 16);
}

__device__ __forceinline__ unsigned cvt_pk_bf16(float lo, float hi) {
    unsigned r;
    asm("v_cvt_pk_bf16_f32 %0, %1, %2" : "=v"(r) : "v"(lo), "v"(hi));
    return r;
}

__device__ __forceinline__ void async_lds16(void* lds, const void* g) {
    __builtin_amdgcn_global_load_lds(
        (const __attribute__((address_space(1))) unsigned int*)g,
        (__attribute__((address_space(3))) unsigned int*)lds, 16, 0, 0);
}

// ---------------------------------------------------------------------------
// fp32 -> bf16 elementwise convert, 8 elems/thread (n divisible by 8)
// ---------------------------------------------------------------------------
__global__ __launch_bounds__(256)
void conv_bf16_kernel(const float* __restrict__ in, u16* __restrict__ out, int n)
{
    int i = (blockIdx.x * 256 + threadIdx.x) * 8;
    if (i >= n) return;
    float4 v0 = *(const float4*)&in[i];
    float4 v1 = *(const float4*)&in[i + 4];
    union { u16 u[8]; uint4 p; } r;
    r.u[0] = f2b(v0.x); r.u[1] = f2b(v0.y); r.u[2] = f2b(v0.z); r.u[3] = f2b(v0.w);
    r.u[4] = f2b(v1.x); r.u[5] = f2b(v1.y); r.u[6] = f2b(v1.z); r.u[7] = f2b(v1.w);
    *(uint4*)&out[i] = r.p;
}

// ---------------------------------------------------------------------------
// Both weight transposes in ONE launch.  z=0: Wqkv[768,2304] -> WqkvT;
// z=1: Wproj[768,768] -> WprojT.  64x64 tiles; z=1 blocks with bx>=12 exit.
// ---------------------------------------------------------------------------
__global__ __launch_bounds__(256)
void transpose2_bf16_kernel(const float* __restrict__ Wq, u16* __restrict__ WqT,
                            const float* __restrict__ Wp, u16* __restrict__ WpT)
{
    const int z = blockIdx.z;
    if (z == 1 && blockIdx.x >= Dn / 64) return;
    const float* W  = z ? Wp : Wq;
    u16* WT         = z ? WpT : WqT;
    const int N     = z ? Dn : D3;
    const int K     = Dn;

    __shared__ float Ls[64][65];
    const int bk = blockIdx.y * 64, bn = blockIdx.x * 64;
    const int r  = threadIdx.x >> 2;
    const int c0 = (threadIdx.x & 3) * 16;
    #pragma unroll
    for (int i = 0; i < 4; ++i) {
        float4 v = *(const float4*)&W[(size_t)(bk + r) * N + bn + c0 + i * 4];
        Ls[r][c0 + i * 4 + 0] = v.x;
        Ls[r][c0 + i * 4 + 1] = v.y;
        Ls[r][c0 + i * 4 + 2] = v.z;
        Ls[r][c0 + i * 4 + 3] = v.w;
    }
    __syncthreads();
    #pragma unroll
    for (int i = 0; i < 16; ++i) {
        WT[(size_t)(bn + r) * K + bk + c0 + i] = f2b(Ls[c0 + i][r]);
    }
}

// ---------------------------------------------------------------------------
// bf16 MFMA GEMM, tile-templated (BM x BN), BK=32, 2-phase stage-early
// double-buffered (round-10/13 verified). <256,128> = QKV config.
// LDS swizzle: per 128B row-pair, slot s = (((row&1)<<2)|chunk) ^ (rp&7).
// 1D grid, XCD-chunked bijective swizzle (nwg%8==0).
// MODE 0: fp32 C.  MODE 1 (QKV): cols<1536 -> bf16 qkv; cols>=1536 -> V
// transposed into VT[b,h,d,t] (packed 4-row 8B stores).
// ---------------------------------------------------------------------------
template <int MODE, int BM, int BN>
__global__ __launch_bounds__((BM / 64) * (BN / 64) * 64)
void gemm_mfma_kernel(const u16* __restrict__ A, const u16* __restrict__ BT,
                      const float* __restrict__ bias, void* __restrict__ Cout,
                      u16* __restrict__ VTout, int M, int N, int K)
{
    constexpr int WN = BN / 64;
    constexpr int T  = (BM / 64) * WN * 64;
    constexpr int ACH = BM * 4;
    constexpr int BCH = BN * 4;

    __shared__ u16 As[2][BM * 32];
    __shared__ u16 Bs[2][BN * 32];
    const int tid  = threadIdx.x;
    const int w    = tid >> 6;
    const int lane = tid & 63;
    const int li   = lane & 15;
    const int g    = lane >> 4;
    const int wm   = w / WN;
    const int wn   = w % WN;

    const int fid = blockIdx.x;
    const int wg  = (fid & 7) * ((int)gridDim.x >> 3) + (fid >> 3);
    const int nbx = N / BN;
    const int bm  = (wg / nbx) * BM;
    const int bn  = (wg % nbx) * BN;

#define GSTAGE(k0s, buf_) do {                                                 \
        _Pragma("unroll")                                                      \
        for (int i_ = 0; i_ < ACH / T; ++i_) {                                 \
            const int L_  = i_ * T + tid;                                      \
            const int rp_ = L_ >> 3;                                           \
            const int u_  = (L_ & 7) ^ (rp_ & 7);                              \
            const int row_ = rp_ * 2 + (u_ >> 2);                              \
            const int gc_  = u_ & 3;                                           \
            async_lds16(&As[buf_][(i_ * T + w * 64) * 8],                      \
                        &A[(size_t)(bm + row_) * K + (k0s) + gc_ * 8]);        \
        }                                                                      \
        _Pragma("unroll")                                                      \
        for (int i_ = 0; i_ < BCH / T; ++i_) {                                 \
            const int L_  = i_ * T + tid;                                      \
            const int rp_ = L_ >> 3;                                           \
            const int u_  = (L_ & 7) ^ (rp_ & 7);                              \
            const int row_ = rp_ * 2 + (u_ >> 2);                              \
            const int gc_  = u_ & 3;                                           \
            async_lds16(&Bs[buf_][(i_ * T + w * 64) * 8],                      \
                        &BT[(size_t)(bn + row_) * K + (k0s) + gc_ * 8]);       \
        }                                                                      \
    } while (0)

    f32x4 acc[4][4];
    #pragma unroll
    for (int i = 0; i < 4; ++i)
        #pragma unroll
        for (int j = 0; j < 4; ++j)
            acc[i][j] = (f32x4){0.f, 0.f, 0.f, 0.f};

    GSTAGE(0, 0);
    __syncthreads();

    const int nk = K / 32;
    for (int kt = 0; kt < nk; ++kt) {
        const int cur = kt & 1;
        if (kt + 1 < nk) GSTAGE((kt + 1) * 32, cur ^ 1);

        bf16x8 af[4], bfr[4];
        #pragma unroll
        for (int fm = 0; fm < 4; ++fm) {
            const int row = wm * 64 + fm * 16 + li;
            const int rp  = row >> 1;
            const int s   = (((row & 1) << 2) | g) ^ (rp & 7);
            af[fm] = *(const bf16x8*)&As[cur][rp * 64 + s * 8];
        }
        #pragma unroll
        for (int fn = 0; fn < 4; ++fn) {
            const int row = wn * 64 + fn * 16 + li;
            const int rp  = row >> 1;
            const int s   = (((row & 1) << 2) | g) ^ (rp & 7);
            bfr[fn] = *(const bf16x8*)&Bs[cur][rp * 64 + s * 8];
        }
        __builtin_amdgcn_s_setprio(1);
        #pragma unroll
        for (int fm = 0; fm < 4; ++fm)
            #pragma unroll
            for (int fn = 0; fn < 4; ++fn)
                acc[fm][fn] = __builtin_amdgcn_mfma_f32_16x16x32_bf16(
                    af[fm], bfr[fn], acc[fm][fn], 0, 0, 0);
        __builtin_amdgcn_s_setprio(0);

        __syncthreads();
    }
#undef GSTAGE

    if (MODE == 1 && bn >= 2 * Dn) {
        #pragma unroll
        for (int fm = 0; fm < 4; ++fm) {
            const int t0g = bm + wm * 64 + fm * 16 + g * 4;
            const int bb = t0g >> 10, tt = t0g & 1023;
            #pragma unroll
            for (int fn = 0; fn < 4; ++fn) {
                const int ncol = bn + wn * 64 + fn * 16 + li;
                const float bs = bias[ncol];
                const int cv = ncol - 2 * Dn;
                const int hv = cv >> 6, dv = cv & 63;
                union { u16 u[4]; uint2 p; } r;
                #pragma unroll
                for (int reg = 0; reg < 4; ++reg)
                    r.u[reg] = f2b(acc[fm][fn][reg] + bs);
                *(uint2*)&VTout[(((size_t)bb * Hn + hv) * HDn + dv) * Tn + tt] = r.p;
            }
        }
    } else {
        #pragma unroll
        for (int fm = 0; fm < 4; ++fm) {
            #pragma unroll
            for (int reg = 0; reg < 4; ++reg) {
                const size_t row = (size_t)(bm + wm * 64 + fm * 16 + g * 4 + reg);
                #pragma unroll
                for (int fn = 0; fn < 4; ++fn) {
                    const int col = bn + wn * 64 + fn * 16 + li;
                    const float v = acc[fm][fn][reg] + bias[col];
                    if (MODE == 1) ((u16*)Cout)[row * N + col] = f2b(v);
                    else           ((float*)Cout)[row * N + col] = v;
                }
            }
        }
    }
}

// ---------------------------------------------------------------------------
// Proj GEMM probe: 128x128, BK=64, stage-early double-buffered. 64 KB LDS
// (2 blocks/CU). Per barrier period: 32 MFMA + 16 ds_read per wave (~700cyc
// across 2 blocks/CU) -- covers the ~500-600cyc stage latency that BK=32's
// shorter period exposes (the attn kernel's proven mechanism).
// LDS layout: 64-elem rows, octet swizzle o^(row&7) (attn-verified pattern).
// fp32 C + bias.  1D grid, XCD-chunked swizzle (nwg%8==0).
// ---------------------------------------------------------------------------
__global__ __launch_bounds__(256)
void gemm_bk64_kernel(const u16* __restrict__ A, const u16* __restrict__ BT,
                      const float* __restrict__ bias, float* __restrict__ C,
                      int M, int N, int K)
{
    __shared__ u16 As[2][128 * 64];   // 16 KB per buffer
    __shared__ u16 Bs[2][128 * 64];
    const int tid  = threadIdx.x;
    const int w    = tid >> 6;
    const int lane = tid & 63;
    const int li   = lane & 15;
    const int g    = lane >> 4;
    const int wm   = w >> 1, wn = w & 1;

    const int fid = blockIdx.x;
    const int wg  = (fid & 7) * ((int)gridDim.x >> 3) + (fid >> 3);
    const int nbx = N / 128;
    const int bm  = (wg / nbx) * 128;
    const int bn  = (wg % nbx) * 128;

    // stage: 1024 chunks per matrix, 4/thread each. Chunk L: row = L>>3,
    // slot s = L&7 holds global octet s^(row&7) of row.
#define GSTAGE64(k0s, buf_) do {                                               \
        _Pragma("unroll")                                                      \
        for (int i_ = 0; i_ < 4; ++i_) {                                       \
            const int L_   = i_ * 256 + tid;                                   \
            const int row_ = L_ >> 3;                                          \
            const int gp_  = (L_ & 7) ^ (row_ & 7);                            \
            async_lds16(&As[buf_][(i_ * 256 + w * 64) * 8],                    \
                        &A[(size_t)(bm + row_) * K + (k0s) + gp_ * 8]);        \
            async_lds16(&Bs[buf_][(i_ * 256 + w * 64) * 8],                    \
                        &BT[(size_t)(bn + row_) * K + (k0s) + gp_ * 8]);       \
        }                                                                      \
    } while (0)

    f32x4 acc[4][4];
    #pragma unroll
    for (int i = 0; i < 4; ++i)
        #pragma unroll
        for (int j = 0; j < 4; ++j)
            acc[i][j] = (f32x4){0.f, 0.f, 0.f, 0.f};

    GSTAGE64(0, 0);
    __syncthreads();

    const int nk = K / 64;   // 12
    for (int kt = 0; kt < nk; ++kt) {
        const int cur = kt & 1;
        if (kt + 1 < nk) GSTAGE64((kt + 1) * 64, cur ^ 1);

        #pragma unroll
        for (int kk = 0; kk < 2; ++kk) {
            bf16x8 af[4], bfr[4];
            #pragma unroll
            for (int fm = 0; fm < 4; ++fm) {
                const int row = wm * 64 + fm * 16 + li;
                af[fm] = *(const bf16x8*)&As[cur][
                    row * 64 + ((kk * 32 + g * 8) ^ ((li & 7) * 8))];
            }
            #pragma unroll
            for (int fn = 0; fn < 4; ++fn) {
                const int row = wn * 64 + fn * 16 + li;
                bfr[fn] = *(const bf16x8*)&Bs[cur][
                    row * 64 + ((kk * 32 + g * 8) ^ ((li & 7) * 8))];
            }
            __builtin_amdgcn_s_setprio(1);
            #pragma unroll
            for (int fm = 0; fm < 4; ++fm)
                #pragma unroll
                for (int fn = 0; fn < 4; ++fn)
                    acc[fm][fn] = __builtin_amdgcn_mfma_f32_16x16x32_bf16(
                        af[fm], bfr[fn], acc[fm][fn], 0, 0, 0);
            __builtin_amdgcn_s_setprio(0);
        }

        __syncthreads();
    }
#undef GSTAGE64

    #pragma unroll
    for (int fm = 0; fm < 4; ++fm) {
        #pragma unroll
        for (int reg = 0; reg < 4; ++reg) {
            const size_t row = (size_t)(bm + wm * 64 + fm * 16 + g * 4 + reg);
            #pragma unroll
            for (int fn = 0; fn < 4; ++fn) {
                const int col = bn + wn * 64 + fn * 16 + li;
                C[row * N + col] = acc[fm][fn][reg] + bias[col];
            }
        }
    }
}

// ---------------------------------------------------------------------------
// LDS-staged MFMA flash attention (causal), swapped QK^T.  (round-7 verified)
// ---------------------------------------------------------------------------
__global__ __launch_bounds__(256, 3)
void attn_mfma_kernel(const u16* __restrict__ qkvb, const u16* __restrict__ VT,
                      u16* __restrict__ attnb)
{
    __shared__ u16 Ks[2][64 * 64];
    __shared__ u16 Vs[2][64 * 64];
    __shared__ u16 Pb[4][32 * 64];

    const int tid  = threadIdx.x;
    const int w    = tid >> 6;
    const int lane = tid & 63;
    const int li   = lane & 15;
    const int g    = lane >> 4;

    const int fid = blockIdx.x;
    const int xcd = fid & 7, j = fid >> 3;
    const int bh  = xcd + 8 * (j % 12);
    const int qt  = 7 - (j / 12);
    const int b   = bh / 12, h = bh % 12;

    const int q0   = qt * 128;
    const int wrow = q0 + w * 32;
    const size_t rowbase = (size_t)b * Tn;
    const u16* vbase = VT + (size_t)bh * HDn * Tn;
    const u16* kbase = &qkvb[rowbase * D3 + Dn + h * HDn];

#define STAGE(kt_, buf_) do {                                                  \
        const int k0s = (kt_) * 64;                                            \
        _Pragma("unroll")                                                      \
        for (int i_ = 0; i_ < 2; ++i_) {                                       \
            const int L_   = i_ * 256 + tid;                                   \
            const int row_ = L_ >> 3;                                          \
            const int gp_  = (L_ & 7) ^ (row_ & 7);                            \
            async_lds16(&Ks[buf_][(i_ * 256 + w * 64) * 8],                    \
                        &kbase[(size_t)(k0s + row_) * D3 + gp_ * 8]);          \
            async_lds16(&Vs[buf_][(i_ * 256 + w * 64) * 8],                    \
                        &vbase[(size_t)row_ * Tn + k0s + gp_ * 8]);            \
        }                                                                      \
    } while (0)

    STAGE(0, 0);

    bf16x8 qf[2][2];
    #pragma unroll
    for (int rh = 0; rh < 2; ++rh)
        #pragma unroll
        for (int kc = 0; kc < 2; ++kc)
            qf[rh][kc] = *(const bf16x8*)&qkvb[
                (rowbase + wrow + rh * 16 + li) * D3 + h * HDn + kc * 32 + g * 8];

    f32x4 of[2][4];
    float m_run[2], l_run[2];
    #pragma unroll
    for (int rh = 0; rh < 2; ++rh) {
        #pragma unroll
        for (int nf = 0; nf < 4; ++nf) of[rh][nf] = (f32x4){0.f, 0.f, 0.f, 0.f};
        m_run[rh] = -1e30f;
        l_run[rh] = 0.f;
    }

    const int nkt   = (q0 >> 6) + 2;
    const int myend = wrow >> 6;

    __syncthreads();

    for (int kt = 0; kt < nkt; ++kt) {
        const int cur = kt & 1;
        if (kt + 1 < nkt) STAGE(kt + 1, cur ^ 1);

        if (kt <= myend) {
            const int k0 = kt * 64;
            const bool maskit = (kt == myend);

            f32x4 st[2][4];
            #pragma unroll
            for (int rh = 0; rh < 2; ++rh)
                #pragma unroll
                for (int nf = 0; nf < 4; ++nf) st[rh][nf] = (f32x4){0.f, 0.f, 0.f, 0.f};
            __builtin_amdgcn_s_setprio(1);
            #pragma unroll
            for (int kc = 0; kc < 2; ++kc)
                #pragma unroll
                for (int nf = 0; nf < 4; ++nf) {
                    const bf16x8 kf = *(const bf16x8*)&Ks[cur][
                        (nf * 16 + li) * 64 + ((kc * 32 + g * 8) ^ ((li & 7) * 8))];
                    st[0][nf] = __builtin_amdgcn_mfma_f32_16x16x32_bf16(kf, qf[0][kc], st[0][nf], 0, 0, 0);
                    st[1][nf] = __builtin_amdgcn_mfma_f32_16x16x32_bf16(kf, qf[1][kc], st[1][nf], 0, 0, 0);
                }
            __builtin_amdgcn_s_setprio(0);

            #pragma unroll
            for (int rh = 0; rh < 2; ++rh) {
                if (maskit) {
                    const int qg = wrow + rh * 16 + li;
                    #pragma unroll
                    for (int nf = 0; nf < 4; ++nf)
                        #pragma unroll
                        for (int reg = 0; reg < 4; ++reg)
                            if (k0 + nf * 16 + g * 4 + reg > qg) st[rh][nf][reg] = -1e30f;
                }

                float mt = st[rh][0][0];
                #pragma unroll
                for (int nf = 0; nf < 4; ++nf)
                    #pragma unroll
                    for (int reg = 0; reg < 4; ++reg)
                        mt = fmaxf(mt, st[rh][nf][reg]);
                mt = fmaxf(mt, __shfl_xor(mt, 16, 64));
                mt = fmaxf(mt, __shfl_xor(mt, 32, 64));
                const float mts = mt * SM_SCALE;

                const float mold = m_run[rh];
                if (!__all(mts <= mold + 8.0f)) {
                    const float mnew = fmaxf(mold, mts);
                    const float resc = exp2f(mold - mnew);
                    m_run[rh] = mnew;
                    l_run[rh] *= resc;
                    float rs[4];
                    #pragma unroll
                    for (int reg = 0; reg < 4; ++reg)
                        rs[reg] = __shfl(resc, g * 4 + reg, 64);
                    #pragma unroll
                    for (int nf = 0; nf < 4; ++nf)
                        #pragma unroll
                        for (int reg = 0; reg < 4; ++reg)
                            of[rh][nf][reg] *= rs[reg];
                }

                const float mcur = m_run[rh];
                float ls = 0.f;
                u16* pb = &Pb[w][(rh * 16 + li) * 64];
                #pragma unroll
                for (int nf = 0; nf < 4; ++nf) {
                    const float p0 = exp2f(fmaf(st[rh][nf][0], SM_SCALE, -mcur));
                    const float p1 = exp2f(fmaf(st[rh][nf][1], SM_SCALE, -mcur));
                    const float p2 = exp2f(fmaf(st[rh][nf][2], SM_SCALE, -mcur));
                    const float p3 = exp2f(fmaf(st[rh][nf][3], SM_SCALE, -mcur));
                    ls += (p0 + p1) + (p2 + p3);
                    uint2 pk;
                    pk.x = cvt_pk_bf16(p0, p1);
                    pk.y = cvt_pk_bf16(p2, p3);
                    *(uint2*)&pb[(nf * 16 + g * 4) ^ ((li & 7) << 3)] = pk;
                }
                ls += __shfl_xor(ls, 16, 64);
                ls += __shfl_xor(ls, 32, 64);
                l_run[rh] += ls;
            }

            #pragma unroll
            for (int kc = 0; kc < 2; ++kc) {
                const int pcol = (kc * 32 + g * 8) ^ ((li & 7) << 3);
                const bf16x8 pf0 = *(const bf16x8*)&Pb[w][li * 64 + pcol];
                const bf16x8 pf1 = *(const bf16x8*)&Pb[w][(16 + li) * 64 + pcol];
                __builtin_amdgcn_s_setprio(1);
                #pragma unroll
                for (int nf = 0; nf < 4; ++nf) {
                    const bf16x8 vf = *(const bf16x8*)&Vs[cur][
                        (nf * 16 + li) * 64 + ((kc * 32 + g * 8) ^ ((li & 7) * 8))];
                    of[0][nf] = __builtin_amdgcn_mfma_f32_16x16x32_bf16(pf0, vf, of[0][nf], 0, 0, 0);
                    of[1][nf] = __builtin_amdgcn_mfma_f32_16x16x32_bf16(pf1, vf, of[1][nf], 0, 0, 0);
                }
                __builtin_amdgcn_s_setprio(0);
            }
        }

        __syncthreads();
    }
#undef STAGE

    #pragma unroll
    for (int rh = 0; rh < 2; ++rh) {
        const float inv = 1.0f / l_run[rh];
        float rs[4];
        #pragma unroll
        for (int reg = 0; reg < 4; ++reg)
            rs[reg] = __shfl(inv, g * 4 + reg, 64);
        #pragma unroll
        for (int reg = 0; reg < 4; ++reg) {
            const size_t row = rowbase + wrow + rh * 16 + g * 4 + reg;
            #pragma unroll
            for (int nf = 0; nf < 4; ++nf)
                attnb[row * Dn + h * HDn + nf * 16 + li] = f2b(of[rh][nf][reg] * rs[reg]);
        }
    }
}

extern "C" void kernel_launch(void* const* d_in, const int* in_sizes, int n_in,
                              void* d_out, int out_size, void* d_ws, size_t ws_size,
                              hipStream_t stream) {
    const float* x     = (const float*)d_in[0];
    const float* Wqkv  = (const float*)d_in[1];
    const float* bqkv  = (const float*)d_in[2];
    const float* Wproj = (const float*)d_in[3];
    const float* bproj = (const float*)d_in[4];
    float* out = (float*)d_out;

    const int M = Bn * Tn;   // 8192

    char* ws = (char*)d_ws;
    u16* qkvb   = (u16*)ws;  ws += (size_t)M * D3 * 2;        // 37.75 MB
    u16* xb     = (u16*)ws;  ws += (size_t)M * Dn * 2;        // 12.6 MB
    u16* attnb  = (u16*)ws;  ws += (size_t)M * Dn * 2;        // 12.6 MB
    u16* VT     = (u16*)ws;  ws += (size_t)Bn * Hn * HDn * Tn * 2; // 12.6 MB
    u16* WqkvT  = (u16*)ws;  ws += (size_t)D3 * Dn * 2;       // 3.5 MB
    u16* WprojT = (u16*)ws;                                   // 1.2 MB

    conv_bf16_kernel<<<M * Dn / 8 / 256, 256, 0, stream>>>(x, xb, M * Dn);
    {
        dim3 g(D3 / 64, Dn / 64, 2);
        transpose2_bf16_kernel<<<g, 256, 0, stream>>>(Wqkv, WqkvT, Wproj, WprojT);
    }
    {
        const int nwg = (M / 256) * (D3 / 128);   // 576, %8==0
        gemm_mfma_kernel<1, 256, 128><<<nwg, 512, 0, stream>>>(
            xb, WqkvT, bqkv, qkvb, VT, M, D3, Dn);
    }
    attn_mfma_kernel<<<768, 256, 0, stream>>>(qkvb, VT, attnb);
    {
        const int nwg = (M / 128) * (Dn / 128);   // 384, %8==0
        gemm_bk64_kernel<<<nwg, 256, 0, stream>>>(
            attnb, WprojT, bproj, out, M, Dn, Dn);
    }
}